// Round 4
// baseline (3010.814 us; speedup 1.0000x reference)
//
#include <hip/hip_runtime.h>
#include <hip/hip_bf16.h>

// LightGCN propagation on MI355X — fp32 I/O (reference dtypes: float32/int).
// Graph: 150000 nodes (100000 users + 50000 items), 4M directed edges.
// 3 layers: acc <- scatter_add(dis[row]*dis[col] * acc[row] -> col); total += acc.
// Output (fp32, in d_out): total / 4, node order (users then items).
// total accumulates directly in d_out. Edge dtype (int32/int64) detected on device.

#ifndef EMB
#define EMB 64
#endif

static __device__ __forceinline__ void f32_atomic_add(float* p, float v) {
    unsafeAtomicAdd(p, v);   // global_atomic_add_f32 on gfx950
}

// flag = 1 if edge_index is int64 (high words of first 128 entries all zero).
__global__ void lgcn_detect_kernel(const int* __restrict__ ei, int* __restrict__ flag) {
    __shared__ int any_nz;
    if (threadIdx.x == 0) any_nz = 0;
    __syncthreads();
    if (ei[2 * threadIdx.x + 1] != 0) atomicOr(&any_nz, 1);
    __syncthreads();
    if (threadIdx.x == 0) *flag = (any_nz == 0) ? 1 : 0;
}

static __device__ __forceinline__ int load_idx(const int* __restrict__ ei,
                                               long long elem, int is64,
                                               int n_nodes) {
    int v = is64 ? ei[elem << 1] : ei[elem];
    return min(max(v, 0), n_nodes - 1);   // never corrupt memory on a bad read
}

// deg[col[e]] += 1
__global__ void lgcn_deg_kernel(const int* __restrict__ ei,
                                const int* __restrict__ flag,
                                float* __restrict__ deg,
                                int n_edges, int n_nodes) {
    int e = blockIdx.x * blockDim.x + threadIdx.x;
    if (e < n_edges) {
        int c = load_idx(ei, (long long)n_edges + e, *flag, n_nodes);
        f32_atomic_add(&deg[c], 1.0f);
    }
}

// deg -> deg^{-1/2} in place (0 where deg == 0)
__global__ void lgcn_dis_kernel(float* __restrict__ deg, int n_nodes) {
    int i = blockIdx.x * blockDim.x + threadIdx.x;
    if (i < n_nodes) {
        float d = deg[i];
        deg[i] = (d > 0.0f) ? rsqrtf(d) : 0.0f;
    }
}

// total(d_out) = acc = concat(user_w, item_w)   (all fp32)
__global__ void lgcn_init_kernel(const float* __restrict__ user_w,
                                 const float* __restrict__ item_w,
                                 float* __restrict__ total,
                                 float* __restrict__ acc,
                                 int n_user_elems, int n_total_elems) {
    int i = blockIdx.x * blockDim.x + threadIdx.x;
    if (i < n_total_elems) {
        float v = (i < n_user_elems) ? user_w[i] : item_w[i - n_user_elems];
        total[i] = v;
        acc[i]   = v;
    }
}

// One wave (64 lanes) per edge; lane == embedding dim.
// nxt[col][lane] += dis[row]*dis[col] * acc[row][lane]
__global__ void lgcn_scatter_kernel(const int* __restrict__ ei,
                                    const int* __restrict__ flag,
                                    const float* __restrict__ dis,
                                    const float* __restrict__ acc,
                                    float* __restrict__ nxt,
                                    int n_edges, int n_nodes) {
    long long tid = (long long)blockIdx.x * blockDim.x + threadIdx.x;
    int e    = (int)(tid >> 6);    // wave-uniform edge id
    int lane = (int)(tid & 63);
    if (e < n_edges) {
        int is64 = *flag;
        int r = load_idx(ei, (long long)e, is64, n_nodes);            // broadcast
        int c = load_idx(ei, (long long)n_edges + e, is64, n_nodes);  // broadcast
        float nrm = dis[r] * dis[c];
        float v = nrm * acc[r * EMB + lane];   // coalesced 256B gather
        f32_atomic_add(&nxt[c * EMB + lane], v);
    }
}

// total += acc
__global__ void lgcn_accum_kernel(float* __restrict__ total,
                                  const float* __restrict__ acc, int n) {
    int i = blockIdx.x * blockDim.x + threadIdx.x;
    if (i < n) total[i] += acc[i];
}

// total *= 1/(n_layers+1)   (in place, d_out)
__global__ void lgcn_final_kernel(float* __restrict__ total,
                                  float inv_states, int n) {
    int i = blockIdx.x * blockDim.x + threadIdx.x;
    if (i < n) total[i] *= inv_states;
}

extern "C" void kernel_launch(void* const* d_in, const int* in_sizes, int n_in,
                              void* d_out, int out_size, void* d_ws, size_t ws_size,
                              hipStream_t stream) {
    // ---- role assignment by element count (robust to input ordering) ----
    int ie = 0, iu = 1, ii = 2;
    {
        long long s[3] = { in_sizes[0], in_sizes[1], in_sizes[2] };
        ie = 0;
        if (s[1] > s[ie]) ie = 1;
        if (s[2] > s[ie]) ie = 2;
        int rest[2], k = 0;
        for (int j = 0; j < 3; ++j) if (j != ie) rest[k++] = j;
        if (s[rest[0]] >= s[rest[1]]) { iu = rest[0]; ii = rest[1]; }
        else                          { iu = rest[1]; ii = rest[0]; }
    }
    const int*   edge_index = (const int*)d_in[ie];
    const float* user_w     = (const float*)d_in[iu];
    const float* item_w     = (const float*)d_in[ii];
    float* out = (float*)d_out;   // doubles as `total` accumulator

    const int n_edges = in_sizes[ie] / 2;
    const int n_users = in_sizes[iu] / EMB;
    const int n_items = in_sizes[ii] / EMB;
    const int n_nodes = n_users + n_items;
    const int n_elems = n_nodes * EMB;   // == out_size
    const int n_layers = 3;

    // ---- workspace carve: flag | dis | accA | accB  (~77.4 MB) ----
    auto align_up = [](size_t x) { return (x + 1023) & ~(size_t)1023; };
    char* w = (char*)d_ws;
    int*   flag = (int*)w;   w += 1024;
    float* dis  = (float*)w; w += align_up((size_t)n_nodes * sizeof(float));
    float* accA = (float*)w; w += align_up((size_t)n_elems * sizeof(float));
    float* accB = (float*)w;

    const int BLK = 256;
    const int gN = (n_elems + BLK - 1) / BLK;

    // 0) edge dtype detection (every call; deterministic)
    lgcn_detect_kernel<<<1, 128, 0, stream>>>(edge_index, flag);

    // 1) degree + deg^{-1/2}
    hipMemsetAsync(dis, 0, (size_t)n_nodes * sizeof(float), stream);
    lgcn_deg_kernel<<<(n_edges + BLK - 1) / BLK, BLK, 0, stream>>>(
        edge_index, flag, dis, n_edges, n_nodes);
    lgcn_dis_kernel<<<(n_nodes + BLK - 1) / BLK, BLK, 0, stream>>>(dis, n_nodes);

    // 2) init: out = acc = x
    lgcn_init_kernel<<<gN, BLK, 0, stream>>>(
        user_w, item_w, out, accA, n_users * EMB, n_elems);

    // 3) propagation layers
    float* cur = accA;
    float* nxt = accB;
    for (int l = 0; l < n_layers; ++l) {
        hipMemsetAsync(nxt, 0, (size_t)n_elems * sizeof(float), stream);
        long long n_thr = (long long)n_edges * 64;
        int n_blk = (int)((n_thr + BLK - 1) / BLK);
        lgcn_scatter_kernel<<<n_blk, BLK, 0, stream>>>(
            edge_index, flag, dis, cur, nxt, n_edges, n_nodes);
        lgcn_accum_kernel<<<gN, BLK, 0, stream>>>(out, nxt, n_elems);
        float* t = cur; cur = nxt; nxt = t;
    }

    // 4) final average in place
    lgcn_final_kernel<<<gN, BLK, 0, stream>>>(out, 1.0f / (n_layers + 1), n_elems);
}

// Round 5
// 854.787 us; speedup vs baseline: 3.5223x; 3.5223x over previous
//
#include <hip/hip_runtime.h>
#include <hip/hip_bf16.h>

// LightGCN on MI355X — pull-based CSR, no fp32 atomics in the hot path.
//
// Round-4 evidence: scatter kernels wrote 1 GB/layer of 4B atomic write-
// throughs (WRITE_SIZE == 256M*4B exactly) at 294G atomics/s -> 871 us/layer.
// This version builds CSR-by-destination on device (histogram + scan + fill),
// then one wave per destination node pulls+accumulates in registers and
// stores once. Propagation states are bf16 (one 128B cacheline per edge
// gather); `total` stays fp32 in d_out. Error budget: threshold 2.8e-3,
// fp32 version measured 2.4e-4; bf16 intermediates add ~2e-4.

#ifndef EMB
#define EMB 64
#endif
#define SCHUNK 2048   // elements per scan block (256 thr x 8)

// flag = 1 if edge_index is int64 (high words of first 128 entries all zero).
__global__ void lgcn_detect_kernel(const int* __restrict__ ei, int* __restrict__ flag) {
    __shared__ int any_nz;
    if (threadIdx.x == 0) any_nz = 0;
    __syncthreads();
    if (ei[2 * threadIdx.x + 1] != 0) atomicOr(&any_nz, 1);
    __syncthreads();
    if (threadIdx.x == 0) *flag = (any_nz == 0) ? 1 : 0;
}

static __device__ __forceinline__ int load_idx(const int* __restrict__ ei,
                                               long long elem, int is64,
                                               int n_nodes) {
    int v = is64 ? ei[elem << 1] : ei[elem];
    return min(max(v, 0), n_nodes - 1);
}

// deg[col[e]] += 1  (int atomics, 4M ops)
__global__ void lgcn_hist_kernel(const int* __restrict__ ei,
                                 const int* __restrict__ flag,
                                 int* __restrict__ deg,
                                 int n_edges, int n_nodes) {
    int e = blockIdx.x * blockDim.x + threadIdx.x;
    if (e < n_edges) {
        int c = load_idx(ei, (long long)n_edges + e, *flag, n_nodes);
        atomicAdd(&deg[c], 1);
    }
}

// dis[i] = deg>0 ? rsqrt(deg) : 0
__global__ void lgcn_dis_kernel(const int* __restrict__ deg,
                                float* __restrict__ dis, int n_nodes) {
    int i = blockIdx.x * blockDim.x + threadIdx.x;
    if (i < n_nodes) {
        int d = deg[i];
        dis[i] = (d > 0) ? rsqrtf((float)d) : 0.0f;
    }
}

// --- exclusive scan of deg -> offsets, 3 phases ---
// A: per-chunk exclusive scan (chunk = 2048), chunk totals -> partials[b]
__global__ void lgcn_scanA_kernel(const int* __restrict__ deg,
                                  int* __restrict__ offsets,
                                  int* __restrict__ partials, int n) {
    __shared__ int tsum[256];
    const int t = threadIdx.x;
    const int base = blockIdx.x * SCHUNK + t * 8;
    int vals[8];
    int s = 0;
    #pragma unroll
    for (int k = 0; k < 8; ++k) {
        int idx = base + k;
        int v = (idx < n) ? deg[idx] : 0;
        vals[k] = s;          // exclusive within thread
        s += v;
    }
    tsum[t] = s;
    __syncthreads();
    #pragma unroll
    for (int off = 1; off < 256; off <<= 1) {
        int x = (t >= off) ? tsum[t - off] : 0;
        __syncthreads();
        tsum[t] += x;
        __syncthreads();
    }
    int texcl = tsum[t] - s;  // exclusive prefix of this thread within chunk
    #pragma unroll
    for (int k = 0; k < 8; ++k) {
        int idx = base + k;
        if (idx < n) offsets[idx] = texcl + vals[k];
    }
    if (t == 255) partials[blockIdx.x] = tsum[255];
}

// B: single-block exclusive scan of partials (nb <= 256); offsets[n] = total
__global__ void lgcn_scanB_kernel(int* __restrict__ partials,
                                  int* __restrict__ offsets, int nb, int n) {
    __shared__ int tsum[256];
    const int t = threadIdx.x;
    int v = (t < nb) ? partials[t] : 0;
    tsum[t] = v;
    __syncthreads();
    #pragma unroll
    for (int off = 1; off < 256; off <<= 1) {
        int x = (t >= off) ? tsum[t - off] : 0;
        __syncthreads();
        tsum[t] += x;
        __syncthreads();
    }
    if (t < nb) partials[t] = tsum[t] - v;   // exclusive
    if (t == 255) offsets[n] = tsum[255];    // grand total (= n_edges)
}

// C: offsets[i] += partials[chunk(i)]
__global__ void lgcn_scanC_kernel(int* __restrict__ offsets,
                                  const int* __restrict__ partials, int n) {
    int i = blockIdx.x * blockDim.x + threadIdx.x;
    if (i < n) offsets[i] += partials[i / SCHUNK];
}

// fill: csr_rows[offsets[c] + cursor[c]++] = r
__global__ void lgcn_fill_kernel(const int* __restrict__ ei,
                                 const int* __restrict__ flag,
                                 const int* __restrict__ offsets,
                                 int* __restrict__ cursor,
                                 int* __restrict__ csr_rows,
                                 int n_edges, int n_nodes) {
    int e = blockIdx.x * blockDim.x + threadIdx.x;
    if (e < n_edges) {
        int is64 = *flag;
        int r = load_idx(ei, (long long)e, is64, n_nodes);
        int c = load_idx(ei, (long long)n_edges + e, is64, n_nodes);
        int pos = offsets[c] + atomicAdd(&cursor[c], 1);
        csr_rows[pos] = r;
    }
}

// init: out(total,fp32) = x ; xcatb(bf16) = x
__global__ void lgcn_init_kernel(const float* __restrict__ user_w,
                                 const float* __restrict__ item_w,
                                 float* __restrict__ total,
                                 __hip_bfloat16* __restrict__ xcatb,
                                 int n_user_elems, int n_total_elems) {
    int i = blockIdx.x * blockDim.x + threadIdx.x;
    if (i < n_total_elems) {
        float v = (i < n_user_elems) ? user_w[i] : item_w[i - n_user_elems];
        total[i] = v;
        xcatb[i] = __float2bfloat16(v);
    }
}

// One wave per destination node c; lane = embedding dim.
// acc = sum_j dis[r_j] * xin[r_j][lane], then *dis[c].
// LAST=false: xout[c] = bf16(acc); total[c] += acc
// LAST=true : total[c] = (total[c] + acc) * 0.25
template <bool LAST>
__global__ void lgcn_gather_kernel(const int* __restrict__ csr_rows,
                                   const int* __restrict__ offsets,
                                   const float* __restrict__ dis,
                                   const __hip_bfloat16* __restrict__ xin,
                                   __hip_bfloat16* __restrict__ xout,
                                   float* __restrict__ total,
                                   int n_nodes) {
    long long tid = (long long)blockIdx.x * blockDim.x + threadIdx.x;
    int gid  = (int)(tid >> 6);
    int lane = threadIdx.x & 63;
    int c = __builtin_amdgcn_readfirstlane(gid);   // wave-uniform -> s_loads
    if (c >= n_nodes) return;
    int beg = offsets[c];
    int end = offsets[c + 1];
    float dc = dis[c];
    float a0 = 0.f, a1 = 0.f, a2 = 0.f, a3 = 0.f;
    int j = beg;
    for (; j + 4 <= end; j += 4) {
        int r0 = csr_rows[j], r1 = csr_rows[j + 1];
        int r2 = csr_rows[j + 2], r3 = csr_rows[j + 3];
        float w0 = dis[r0], w1 = dis[r1], w2 = dis[r2], w3 = dis[r3];
        a0 += w0 * __bfloat162float(xin[(size_t)r0 * EMB + lane]);
        a1 += w1 * __bfloat162float(xin[(size_t)r1 * EMB + lane]);
        a2 += w2 * __bfloat162float(xin[(size_t)r2 * EMB + lane]);
        a3 += w3 * __bfloat162float(xin[(size_t)r3 * EMB + lane]);
    }
    for (; j < end; ++j) {
        int r = csr_rows[j];
        a0 += dis[r] * __bfloat162float(xin[(size_t)r * EMB + lane]);
    }
    float acc = (((a0 + a1) + (a2 + a3))) * dc;
    size_t o = (size_t)c * EMB + lane;
    if (!LAST) {
        xout[o] = __float2bfloat16(acc);
        total[o] += acc;
    } else {
        total[o] = (total[o] + acc) * 0.25f;
    }
}

extern "C" void kernel_launch(void* const* d_in, const int* in_sizes, int n_in,
                              void* d_out, int out_size, void* d_ws, size_t ws_size,
                              hipStream_t stream) {
    // ---- role assignment by element count ----
    int ie = 0, iu = 1, ii = 2;
    {
        long long s[3] = { in_sizes[0], in_sizes[1], in_sizes[2] };
        ie = 0;
        if (s[1] > s[ie]) ie = 1;
        if (s[2] > s[ie]) ie = 2;
        int rest[2], k = 0;
        for (int j = 0; j < 3; ++j) if (j != ie) rest[k++] = j;
        if (s[rest[0]] >= s[rest[1]]) { iu = rest[0]; ii = rest[1]; }
        else                          { iu = rest[1]; ii = rest[0]; }
    }
    const int*   edge_index = (const int*)d_in[ie];
    const float* user_w     = (const float*)d_in[iu];
    const float* item_w     = (const float*)d_in[ii];
    float* out = (float*)d_out;   // doubles as fp32 `total`

    const int n_edges = in_sizes[ie] / 2;
    const int n_users = in_sizes[iu] / EMB;
    const int n_items = in_sizes[ii] / EMB;
    const int n_nodes = n_users + n_items;
    const int n_elems = n_nodes * EMB;

    // ---- workspace carve (~76 MB) ----
    auto align_up = [](size_t x) { return (x + 1023) & ~(size_t)1023; };
    char* w = (char*)d_ws;
    int*   flag     = (int*)w;   w += 1024;
    int*   deg      = (int*)w;   w += align_up((size_t)n_nodes * sizeof(int));
    float* dis      = (float*)w; w += align_up((size_t)n_nodes * sizeof(float));
    int*   offsets  = (int*)w;   w += align_up(((size_t)n_nodes + 1) * sizeof(int));
    int*   cursor   = (int*)w;   w += align_up((size_t)n_nodes * sizeof(int));
    int*   partials = (int*)w;   w += 4096;
    int*   csr_rows = (int*)w;   w += align_up((size_t)n_edges * sizeof(int));
    __hip_bfloat16* xcatb = (__hip_bfloat16*)w; w += align_up((size_t)n_elems * sizeof(__hip_bfloat16));
    __hip_bfloat16* accA  = (__hip_bfloat16*)w; w += align_up((size_t)n_elems * sizeof(__hip_bfloat16));
    __hip_bfloat16* accB  = (__hip_bfloat16*)w;

    const int BLK = 256;
    const int gE = (n_edges + BLK - 1) / BLK;
    const int gN = (n_elems + BLK - 1) / BLK;
    const int gV = (n_nodes + BLK - 1) / BLK;
    const int nb = (n_nodes + SCHUNK - 1) / SCHUNK;   // scan chunks (74 <= 256)

    // 0) edge dtype detection
    lgcn_detect_kernel<<<1, 128, 0, stream>>>(edge_index, flag);

    // 1) degree histogram + dis
    hipMemsetAsync(deg, 0, (size_t)n_nodes * sizeof(int), stream);
    lgcn_hist_kernel<<<gE, BLK, 0, stream>>>(edge_index, flag, deg, n_edges, n_nodes);
    lgcn_dis_kernel<<<gV, BLK, 0, stream>>>(deg, dis, n_nodes);

    // 2) exclusive scan deg -> offsets
    lgcn_scanA_kernel<<<nb, 256, 0, stream>>>(deg, offsets, partials, n_nodes);
    lgcn_scanB_kernel<<<1, 256, 0, stream>>>(partials, offsets, nb, n_nodes);
    lgcn_scanC_kernel<<<gV, BLK, 0, stream>>>(offsets, partials, n_nodes);

    // 3) CSR fill
    hipMemsetAsync(cursor, 0, (size_t)n_nodes * sizeof(int), stream);
    lgcn_fill_kernel<<<gE, BLK, 0, stream>>>(edge_index, flag, offsets, cursor,
                                             csr_rows, n_edges, n_nodes);

    // 4) init: out = x (fp32), xcatb = bf16(x)
    lgcn_init_kernel<<<gN, BLK, 0, stream>>>(user_w, item_w, out, xcatb,
                                             n_users * EMB, n_elems);

    // 5) 3 pull layers, one wave per node (grid = n_nodes waves)
    {
        long long n_thr = (long long)n_nodes * 64;
        int gW = (int)((n_thr + BLK - 1) / BLK);
        lgcn_gather_kernel<false><<<gW, BLK, 0, stream>>>(
            csr_rows, offsets, dis, xcatb, accA, out, n_nodes);
        lgcn_gather_kernel<false><<<gW, BLK, 0, stream>>>(
            csr_rows, offsets, dis, accA, accB, out, n_nodes);
        lgcn_gather_kernel<true><<<gW, BLK, 0, stream>>>(
            csr_rows, offsets, dis, accB, nullptr, out, n_nodes);
    }
}